// Round 10
// baseline (522.296 us; speedup 1.0000x reference)
//
#include <hip/hip_runtime.h>
#include <stdint.h>

typedef __attribute__((ext_vector_type(8))) __bf16 bf16x8;
typedef __attribute__((ext_vector_type(2))) __bf16 bf16x2;
typedef __attribute__((ext_vector_type(4))) float f32x4;
typedef __attribute__((ext_vector_type(16))) float f32x16;
typedef unsigned short u16;

#define LOG2E 1.44269504088896f

static_assert(sizeof(bf16x8) == 16, "bf16x8 must be 16B");

__device__ __forceinline__ u16 f2bf(float f) {
  unsigned u = __builtin_bit_cast(unsigned, f);
  u += 0x7fffu + ((u >> 16) & 1u);   // round-to-nearest-even
  return (u16)(u >> 16);
}

__device__ __forceinline__ float bf2f(u16 b) {
  unsigned u = ((unsigned)b) << 16;
  return __builtin_bit_cast(float, u);
}

__device__ __forceinline__ void load_lds16(const void* g, void* l) {
  __builtin_amdgcn_global_load_lds((const __attribute__((address_space(1))) void*)g,
                                   (__attribute__((address_space(3))) void*)l, 16, 0, 0);
}

// ---------------- prep: tmp = W @ A  ([1280,1280]@[1280,4]) ----------------
__global__ __launch_bounds__(256) void lora_tmp_k(
    const float* __restrict__ wk, const float* __restrict__ wv,
    const float* __restrict__ ka, const float* __restrict__ va,
    float* __restrict__ tk, float* __restrict__ tv) {
  const int i = blockIdx.x;
  const float* W = blockIdx.y ? wv : wk;
  const float* A = blockIdx.y ? va : ka;
  float* T = blockIdx.y ? tv : tk;
  float s0 = 0.f, s1 = 0.f, s2 = 0.f, s3 = 0.f;
  for (int j = threadIdx.x; j < 1280; j += 256) {
    float w = W[(size_t)i * 1280 + j];
    float4 a4 = *(const float4*)(A + (size_t)j * 4);
    s0 += w * a4.x; s1 += w * a4.y; s2 += w * a4.z; s3 += w * a4.w;
  }
#pragma unroll
  for (int m = 1; m < 64; m <<= 1) {
    s0 += __shfl_xor(s0, m); s1 += __shfl_xor(s1, m);
    s2 += __shfl_xor(s2, m); s3 += __shfl_xor(s3, m);
  }
  __shared__ float red[4][4];
  const int wv_ = threadIdx.x >> 6;
  if ((threadIdx.x & 63) == 0) {
    red[wv_][0] = s0; red[wv_][1] = s1; red[wv_][2] = s2; red[wv_][3] = s3;
  }
  __syncthreads();
  if (threadIdx.x < 4) {
    float r = red[0][threadIdx.x] + red[1][threadIdx.x] + red[2][threadIdx.x] + red[3][threadIdx.x];
    T[(size_t)i * 4 + threadIdx.x] = r;
  }
}

// --- prep (fused x4): WT[z][o][i] = bf16( W_z[i][o] + lora_z ) , z=0..3 ----
__global__ void wt_prep_k(const float* __restrict__ wq, const float* __restrict__ wk,
                          const float* __restrict__ wv, const float* __restrict__ wo,
                          const float* __restrict__ tk, const float* __restrict__ tv,
                          const float* __restrict__ lkb, const float* __restrict__ lvb,
                          u16* __restrict__ WTbase) {
  const int z = blockIdx.z;
  const float* W = (z == 0) ? wq : (z == 1) ? wk : (z == 2) ? wv : wo;
  const float* tmp = (z == 1) ? tk : (z == 2) ? tv : nullptr;
  const float* LB = (z == 1) ? lkb : (z == 2) ? lvb : nullptr;
  u16* WT = WTbase + (size_t)z * 1638400;
  __shared__ float tile[32][33];
  const int o0 = blockIdx.x * 32, i0 = blockIdx.y * 32;
  const int tx = threadIdx.x, ty = threadIdx.y;
#pragma unroll
  for (int kk = 0; kk < 4; ++kk) {
    int i = i0 + ty + kk * 8, o = o0 + tx;
    float v = W[(size_t)i * 1280 + o];
    if (tmp) {
      float4 t = *(const float4*)(tmp + (size_t)i * 4);
      v += t.x * LB[o] + t.y * LB[1280 + o] + t.z * LB[2560 + o] + t.w * LB[3840 + o];
    }
    tile[ty + kk * 8][tx] = v;
  }
  __syncthreads();
#pragma unroll
  for (int kk = 0; kk < 4; ++kk) {
    int o = o0 + ty + kk * 8, i = i0 + tx;
    WT[(size_t)o * 1280 + i] = f2bf(tile[tx][ty + kk * 8]);
  }
}

// ---------------- fp32 -> bf16 convert (float4 vectorized) ----------------
__global__ __launch_bounds__(256) void cvt_bf16_k(const float* __restrict__ in,
                                                  u16* __restrict__ out, int n4) {
  for (int i = blockIdx.x * 256 + threadIdx.x; i < n4; i += gridDim.x * 256) {
    float4 v = ((const float4*)in)[i];
    ushort4 o;
    o.x = f2bf(v.x); o.y = f2bf(v.y); o.z = f2bf(v.z); o.w = f2bf(v.w);
    ((ushort4*)out)[i] = o;
  }
}

// --------- V [B*S,1280] -> VT [B*1280, 4096] (bf16 tiled transpose) --------
__global__ void vtrans_k(const u16* __restrict__ V, u16* __restrict__ VT) {
  __shared__ u16 tile[32][33];
  const int s0 = blockIdx.x * 32, c0 = blockIdx.y * 32, b = blockIdx.z;
  const int tx = threadIdx.x, ty = threadIdx.y;
#pragma unroll
  for (int kk = 0; kk < 4; ++kk)
    tile[ty + kk * 8][tx] = V[(size_t)(b * 4096 + s0 + ty + kk * 8) * 1280 + c0 + tx];
  __syncthreads();
#pragma unroll
  for (int kk = 0; kk < 4; ++kk)
    VT[(size_t)(b * 1280 + c0 + ty + kk * 8) * 4096 + s0 + tx] = tile[tx][ty + kk * 8];
}

// ------------------- 128x128-tile bf16 MFMA GEMM (BK=32) -------------------
template <bool F32OUT, bool FUSED3>
__global__ __launch_bounds__(256) void gemm128_k(
    const u16* __restrict__ A, const u16* __restrict__ WT,
    void* __restrict__ outp, const float* __restrict__ bias, float oscale) {
  __shared__ __align__(16) u16 lds[2 * 128 * 40];
  u16* ldsA = lds;
  u16* ldsB = lds + 128 * 40;
  const int tid = threadIdx.x;
  const int lane = tid & 63, lrow = lane & 15, lhi = lane >> 4;
  const int w = tid >> 6, wm = w >> 1, wn = w & 1;
  const size_t M0 = (size_t)blockIdx.x * 128, N0 = (size_t)blockIdx.y * 128;
  const int wb = tid & 192;
  f32x4 acc[4][4] = {};

  for (int k0 = 0; k0 < 1280; k0 += 32) {
#pragma unroll
    for (int j = 0; j < 3; ++j) {
      if (j < 2 || tid < 128) {
        int i = j * 256 + tid;
        int row = i / 5, c = i % 5; c = c < 4 ? c : 3;
        load_lds16(A + (M0 + row) * 1280 + k0 + c * 8, ldsA + (j * 256 + wb) * 8);
      }
    }
#pragma unroll
    for (int j = 0; j < 3; ++j) {
      if (j < 2 || tid < 128) {
        int i = j * 256 + tid;
        int row = i / 5, c = i % 5; c = c < 4 ? c : 3;
        load_lds16(WT + (N0 + row) * 1280 + k0 + c * 8, ldsB + (j * 256 + wb) * 8);
      }
    }
    __syncthreads();
    bf16x8 af[4], bfr[4];
#pragma unroll
    for (int m = 0; m < 4; ++m)
      af[m] = *(const bf16x8*)(ldsA + (wm * 64 + m * 16 + lrow) * 40 + lhi * 8);
#pragma unroll
    for (int n = 0; n < 4; ++n)
      bfr[n] = *(const bf16x8*)(ldsB + (wn * 64 + n * 16 + lrow) * 40 + lhi * 8);
#pragma unroll
    for (int m = 0; m < 4; ++m)
#pragma unroll
      for (int n = 0; n < 4; ++n)
        acc[m][n] = __builtin_amdgcn_mfma_f32_16x16x32_bf16(af[m], bfr[n], acc[m][n], 0, 0, 0);
    __syncthreads();
  }

  const float sc = FUSED3 ? (N0 < 1280 ? oscale : 1.0f) : oscale;
  const size_t obase = FUSED3 ? (size_t)(N0 / 1280) * 10485760 : 0;
  const size_t ncol0 = FUSED3 ? (N0 % 1280) : N0;
#pragma unroll
  for (int m = 0; m < 4; ++m)
#pragma unroll
    for (int n = 0; n < 4; ++n)
#pragma unroll
      for (int r = 0; r < 4; ++r) {
        size_t row = M0 + wm * 64 + m * 16 + lhi * 4 + r;
        size_t col = ncol0 + wn * 64 + n * 16 + lrow;
        float v = acc[m][n][r];
        if (F32OUT)
          ((float*)outp)[row * 1280 + col] = v + bias[col];
        else
          ((u16*)outp)[obase + row * 1280 + col] = f2bf(v * sc);
      }
}

// --------------------------- flash attention (seq-split 2) -----------------
// grid 1024 (16 bh x 32 qt x 2 halves, XCD-swizzled), 256 thr = 4 waves x 32
// q-cols. QBLK=128, KVBLK=32, each block covers 2048 kv (one half).
// LDS: K dbuf 2x12288B (32 rows x 24 swizzled 16B chunks) + V pair buffer
// 20480B ([160 rows][64 u16], row stride 64) = 45056 B -> 3 blocks/CU =
// 12 waves/CU (3/SIMD) to lift MfmaUtil past the 2-wave/SIMD 37% ceiling.
// R9 bug fixed: PV read stride was 128 (R7 leftover); buffer is stride 64 —
// rows >=80 read past the LDS allocation -> absmax 1.47. Now row_*64.
// Counted vmcnt from per-wave issue counts (K=3, V=5); every LDS write
// barrier-separated from its last cross-wave read.
// Emits normalized Y=O/l (bf16) + (m,l) per q; merge_k combines halves.

#define QK_CLUSTER(KCUR)                                                        \
  {                                                                             \
    f32x16 zz = {};                                                             \
    sacc0 = zz;                                                                 \
    __builtin_amdgcn_s_setprio(1);                                              \
    _Pragma("unroll")                                                           \
    for (int kf = 0; kf < 10; ++kf) {                                           \
      const int c_ = 2 * kf + lhi5;                                             \
      const int slot_ = (c_ < 16) ? ((c_ & 24) | ((c_ ^ l31) & 7))              \
                                  : (16 + (((c_ - 16) ^ (l31 & 7)) & 7));       \
      bf16x8 ka_ = *(const bf16x8*)((KCUR) + l31 * 192 + slot_ * 8);            \
      sacc0 = __builtin_amdgcn_mfma_f32_32x32x16_bf16(ka_, qf[kf], sacc0, 0, 0, 0); \
    }                                                                           \
    __builtin_amdgcn_s_setprio(0);                                              \
  }

#define PV_CLUSTER(SS)                                                          \
  {                                                                             \
    __builtin_amdgcn_s_setprio(1);                                              \
    _Pragma("unroll")                                                           \
    for (int kf = 0; kf < 2; ++kf) {                                            \
      const int base_ = kf * 4;                                                 \
      unsigned xa_ = xp[base_ + 0], xb_ = xp[base_ + 1];                        \
      unsigned xc_ = xp[base_ + 2], xd_ = xp[base_ + 3];                        \
      unsigned sa_ = __shfl_xor((int)xa_, 32), sb_ = __shfl_xor((int)xb_, 32);  \
      unsigned sc_ = __shfl_xor((int)xc_, 32), sd_ = __shfl_xor((int)xd_, 32);  \
      uint4 pw_;                                                                \
      pw_.x = lo32 ? xa_ : sc_;                                                 \
      pw_.y = lo32 ? xb_ : sd_;                                                 \
      pw_.z = lo32 ? sa_ : xc_;                                                 \
      pw_.w = lo32 ? sb_ : xd_;                                                 \
      bf16x8 pB_ = __builtin_bit_cast(bf16x8, pw_);                             \
      const int c_ = (SS) * 4 + 2 * kf + lhi5;                                  \
      _Pragma("unroll")                                                         \
      for (int dm = 0; dm < 5; ++dm) {                                          \
        const int row_ = dm * 32 + l31;                                         \
        bf16x8 va_ = *(const bf16x8*)(vt + row_ * 64 + ((c_ ^ (row_ & 7)) * 8)); \
        o[dm] = __builtin_amdgcn_mfma_f32_32x32x16_bf16(va_, pB_, o[dm], 0, 0, 0); \
      }                                                                         \
    }                                                                           \
    __builtin_amdgcn_s_setprio(0);                                              \
  }

#define SOFTMAX_STEP()                                                          \
  {                                                                             \
    float tmx_[8];                                                              \
    _Pragma("unroll")                                                           \
    for (int i = 0; i < 8; ++i) tmx_[i] = fmaxf(sacc0[i], sacc0[i + 8]);        \
    float mx_ = fmaxf(fmaxf(fmaxf(tmx_[0], tmx_[1]), fmaxf(tmx_[2], tmx_[3])),  \
                      fmaxf(fmaxf(tmx_[4], tmx_[5]), fmaxf(tmx_[6], tmx_[7]))); \
    mx_ = fmaxf(mx_, __shfl_xor(mx_, 32));                                      \
    if (__any(mx_ - m_run > 8.0f)) {                                            \
      float mnew_ = fmaxf(m_run, mx_);                                          \
      float al_ = __builtin_amdgcn_exp2f((m_run - mnew_) * LOG2E);              \
      l_run *= al_; m_run = mnew_; mLog = m_run * LOG2E;                        \
      _Pragma("unroll")                                                         \
      for (int dm = 0; dm < 5; ++dm)                                            \
        _Pragma("unroll")                                                       \
        for (int i = 0; i < 16; ++i) o[dm][i] *= al_;                           \
    }                                                                           \
    float rs0_ = 0.f, rs1_ = 0.f, rs2_ = 0.f, rs3_ = 0.f;                       \
    _Pragma("unroll")                                                           \
    for (int r = 0; r < 8; ++r) {                                               \
      float p0_ = __builtin_amdgcn_exp2f(fmaf(sacc0[2 * r], LOG2E, -mLog));     \
      float p1_ = __builtin_amdgcn_exp2f(fmaf(sacc0[2 * r + 1], LOG2E, -mLog)); \
      if ((r & 3) == 0) rs0_ += p0_ + p1_;                                      \
      else if ((r & 3) == 1) rs1_ += p0_ + p1_;                                 \
      else if ((r & 3) == 2) rs2_ += p0_ + p1_;                                 \
      else rs3_ += p0_ + p1_;                                                   \
      bf16x2 pk_; pk_[0] = (__bf16)p0_; pk_[1] = (__bf16)p1_;                   \
      xp[r] = __builtin_bit_cast(unsigned, pk_);                                \
    }                                                                           \
    float rs_ = (rs0_ + rs1_) + (rs2_ + rs3_);                                  \
    rs_ += __shfl_xor(rs_, 32);                                                 \
    l_run += rs_;                                                               \
  }

// K stage: 32 rows x 24 chunk-slots = 768 chunks, 3/thread uniform.
// Store-side inverse swizzle; slots whose tail image falls outside chunks
// 16..19 get a harmless duplicate of chunk 19 (reads never touch them).
#define STAGE_K(T, DST)                                                         \
  {                                                                             \
    _Pragma("unroll")                                                           \
    for (int j = 0; j < 3; ++j) {                                               \
      int i_ = j * 256 + tid;                                                   \
      int row_ = i_ / 24, cl_ = i_ % 24;                                        \
      int cg_;                                                                  \
      if (cl_ < 16) cg_ = (cl_ & 24) | ((cl_ ^ row_) & 7);                      \
      else { int v_ = (cl_ - 16) ^ (row_ & 7); cg_ = (v_ < 4) ? 16 + v_ : 19; } \
      load_lds16(Kg + (size_t)((T) * 32 + row_) * 1280 + cg_ * 8,               \
                 (DST) + (j * 256 + wb) * 8);                                   \
    }                                                                           \
  }

// V pair stage: 160 rows x 8 chunks = 1280, 5/thread uniform.
#define STAGE_V(P)                                                              \
  {                                                                             \
    _Pragma("unroll")                                                           \
    for (int j = 0; j < 5; ++j) {                                               \
      int i_ = j * 256 + tid;                                                   \
      int row_ = i_ >> 3, cl_ = i_ & 7;                                         \
      int cg_ = cl_ ^ (row_ & 7);                                               \
      load_lds16(VTg + (size_t)row_ * 4096 + (P) * 64 + cg_ * 8,                \
                 vt + (j * 256 + wb) * 8);                                      \
    }                                                                           \
  }

#define WAITB(N)                                                                \
  asm volatile("s_waitcnt vmcnt(" #N ")" ::: "memory");                         \
  __builtin_amdgcn_s_barrier();                                                 \
  __builtin_amdgcn_sched_barrier(0);

__global__ __launch_bounds__(256, 3) void attn_k(
    const u16* __restrict__ Q, const u16* __restrict__ K,
    const u16* __restrict__ VT, u16* __restrict__ Y0g, u16* __restrict__ Y1g,
    float2* __restrict__ ML) {
  __shared__ __align__(16) u16 lds_all[22528];  // kb0[6144] kb1[6144] vt[10240] u16
  u16* const kb0 = lds_all;
  u16* const kb1 = lds_all + 6144;
  u16* const vt = lds_all + 12288;
  const int tid = threadIdx.x;
  const int lane = tid & 63;
  const int l31 = lane & 31, lhi5 = lane >> 5;
  const int lo32 = (lane < 32);
  const int w = tid >> 6;
  // XCD swizzle: 1024 blocks, XCD k hosts heads {2k,2k+1}
  const int nid = ((blockIdx.x & 7) << 7) | (blockIdx.x >> 3);
  const int bh = nid >> 6, rem = nid & 63;
  const int half = rem >> 5, qt = rem & 31;
  const int b = bh >> 3, h = bh & 7;
  const int wb = tid & 192;

  const u16* Kg = K + (size_t)(b * 4096 + half * 2048) * 1280 + h * 160;
  const u16* VTg = VT + ((size_t)b * 1280 + h * 160) * 4096 + half * 2048;

  // Q -> registers in B-frag layout: lane l31 = q col, k = lhi5*8 + reg
  bf16x8 qf[10];
  const u16* Qg = Q + (size_t)(b * 4096 + qt * 128 + w * 32 + l31) * 1280 + h * 160 + lhi5 * 8;
#pragma unroll
  for (int kf = 0; kf < 10; ++kf) qf[kf] = *(const bf16x8*)(Qg + kf * 16);
#pragma unroll
  for (int kf = 0; kf < 10; ++kf) asm volatile("" : "+v"(qf[kf]));  // drain Q before staging

  f32x16 o[5] = {};
  f32x16 sacc0;
  unsigned xp[8];
  float m_run = -1e30f, l_run = 0.f;
  float mLog = m_run * LOG2E;

  // ---- t = 0 head ----
  STAGE_K(0, kb0);
  WAITB(0);
  STAGE_V(0);        // V first (oldest) ...
  STAGE_K(1, kb1);   // ... then K(1): outstanding V[5] older than K[3]
  QK_CLUSTER(kb0);
  SOFTMAX_STEP();
  WAITB(3);          // V(0) landed (drain 5 oldest = V); K(1) in flight
  PV_CLUSTER(0);

  // ---- odd t=1 (p=0) ----
  WAITB(0);          // K(1) landed
  STAGE_K(2, kb0);
  QK_CLUSTER(kb1);
  SOFTMAX_STEP();
  PV_CLUSTER(1);
  __builtin_amdgcn_s_barrier();  // all PV reads of V pair 0 done
  __builtin_amdgcn_sched_barrier(0);
  STAGE_V(1);

  // ---- pairs p = 1..31 ----
  for (int p = 1; p < 32; ++p) {
    // even t=2p: outstanding K(2p)[3, older] + V(p)[5, newer]
    WAITB(5);        // K(2p) landed
    STAGE_K(2 * p + 1, kb1);
    QK_CLUSTER(kb0);
    SOFTMAX_STEP();
    WAITB(3);        // V(p) landed; K(2p+1) in flight
    PV_CLUSTER(0);
    // odd t=2p+1
    WAITB(0);        // K(2p+1) landed
    if (p < 31) STAGE_K(2 * p + 2, kb0);
    QK_CLUSTER(kb1);
    SOFTMAX_STEP();
    PV_CLUSTER(1);
    __builtin_amdgcn_s_barrier();
    __builtin_amdgcn_sched_barrier(0);
    if (p < 31) STAGE_V(p + 1);
  }

  // ---- epilogue: normalized Y=O/l (bf16) via per-wave LDS transpose ----
  float invl = 1.f / l_run;
  u16* tr = lds_all + w * 5376;  // 32 rows x 168 u16 (slices end at 21504 <= 22528)
#pragma unroll
  for (int dm = 0; dm < 5; ++dm)
#pragma unroll
    for (int k = 0; k < 4; ++k) {
      int d = dm * 32 + k * 8 + lhi5 * 4;
      unsigned lo_ = (unsigned)f2bf(o[dm][4 * k + 0] * invl) |
                     ((unsigned)f2bf(o[dm][4 * k + 1] * invl) << 16);
      unsigned hi_ = (unsigned)f2bf(o[dm][4 * k + 2] * invl) |
                     ((unsigned)f2bf(o[dm][4 * k + 3] * invl) << 16);
      uint2 u; u.x = lo_; u.y = hi_;
      *(uint2*)(tr + l31 * 168 + d) = u;
    }
  asm volatile("s_waitcnt lgkmcnt(0)" ::: "memory");
  __builtin_amdgcn_sched_barrier(0);
  u16* Yw = half ? Y1g : Y0g;
  const size_t qg0 = (size_t)(b * 4096 + qt * 128 + w * 32);
#pragma unroll
  for (int it = 0; it < 10; ++it) {
    int idx = it * 64 + lane;
    int row = idx / 20, cc = idx % 20;
    bf16x8 vch = *(const bf16x8*)(tr + row * 168 + cc * 8);
    *(bf16x8*)(Yw + (qg0 + row) * 1280 + h * 160 + cc * 8) = vch;
  }
  if (lo32) {
    float2 ml; ml.x = m_run; ml.y = l_run;
    ML[((size_t)(half * 16 + bh)) * 4096 + qt * 128 + w * 32 + l31] = ml;
  }
}

// ------------- merge halves: out = w0*Y0 + w1*Y1 (convex combo) ------------
__global__ __launch_bounds__(256) void merge_k(
    const u16* __restrict__ Y0, const u16* __restrict__ Y1,
    const float2* __restrict__ ML, u16* __restrict__ OUT) {
  const int total = 8192 * 160;  // 8-bf16 chunks
  for (int c = blockIdx.x * 256 + threadIdx.x; c < total; c += gridDim.x * 256) {
    int row = c / 160, dc = c % 160;
    int h = dc / 20;
    int b = row >> 12, q = row & 4095;
    size_t mlbase = (size_t)(b * 8 + h) * 4096 + q;
    float2 ml0 = ML[mlbase];
    float2 ml1 = ML[(size_t)16 * 4096 + mlbase];
    float m = fmaxf(ml0.x, ml1.x);
    float a0 = ml0.y * __builtin_amdgcn_exp2f((ml0.x - m) * LOG2E);
    float a1 = ml1.y * __builtin_amdgcn_exp2f((ml1.x - m) * LOG2E);
    float inv = 1.f / (a0 + a1);
    float w0 = a0 * inv, w1 = a1 * inv;
    uint4 ya = ((const uint4*)Y0)[c];
    uint4 yb = ((const uint4*)Y1)[c];
    uint4 yo;
    unsigned* pa = (unsigned*)&ya;
    unsigned* pb = (unsigned*)&yb;
    unsigned* po = (unsigned*)&yo;
#pragma unroll
    for (int k = 0; k < 4; ++k) {
      float a_lo = bf2f((u16)(pa[k] & 0xffff)), a_hi = bf2f((u16)(pa[k] >> 16));
      float b_lo = bf2f((u16)(pb[k] & 0xffff)), b_hi = bf2f((u16)(pb[k] >> 16));
      unsigned lo = f2bf(a_lo * w0 + b_lo * w1);
      unsigned hi = f2bf(a_hi * w0 + b_hi * w1);
      po[k] = lo | (hi << 16);
    }
    ((uint4*)OUT)[c] = yo;
  }
}

// ---------------------------------------------------------------------------
extern "C" void kernel_launch(void* const* d_in, const int* in_sizes, int n_in,
                              void* d_out, int out_size, void* d_ws, size_t ws_size,
                              hipStream_t stream) {
  const float* hs  = (const float*)d_in[0];
  const float* w_q = (const float*)d_in[1];
  const float* w_k = (const float*)d_in[2];
  const float* w_v = (const float*)d_in[3];
  const float* lka = (const float*)d_in[4];
  const float* lkb = (const float*)d_in[5];
  const float* lva = (const float*)d_in[6];
  const float* lvb = (const float*)d_in[7];
  const float* w_o = (const float*)d_in[8];
  const float* b_o = (const float*)d_in[9];
  float* out = (float*)d_out;
  char* ws = (char*)d_ws;

  const size_t KA  = 0;                      // 1280*4 f32
  const size_t VA  = 20480;
  const size_t WTQ = 40960;                  // 1280*1280 bf16 each; Q,K,V,O contiguous
  const size_t WTO = WTQ + 3 * 3276800;
  const size_t HSB = WTO + 3276800;          // 8192*1280 bf16 each below; q,k,v contiguous
  const size_t QB  = HSB + 20971520;
  const size_t KB  = QB + 20971520;
  const size_t VB  = KB + 20971520;
  const size_t VTB = VB + 20971520;
  const size_t AOB = VTB + 20971520;
  const size_t END = AOB + 20971520;
  if (ws_size < END) return;  // leaves poison -> clear validation failure

  float* tk = (float*)(ws + KA);
  float* tv = (float*)(ws + VA);
  u16* wtq = (u16*)(ws + WTQ);
  u16* wto = (u16*)(ws + WTO);
  u16* hsb = (u16*)(ws + HSB);
  u16* qb  = (u16*)(ws + QB);
  u16* kb  = (u16*)(ws + KB);
  u16* vb  = (u16*)(ws + VB);
  u16* vtb = (u16*)(ws + VTB);
  u16* aob = (u16*)(ws + AOB);
  // reuse: Y0 = aob, Y1 = vb (dead after vtrans), ML = hsb (dead after QKV
  // gemm), merged output = vtb (dead after attn)
  float2* ml = (float2*)hsb;
  u16* merged = vtb;

  lora_tmp_k<<<dim3(1280, 2), 256, 0, stream>>>(w_k, w_v, lka, lva, tk, tv);
  wt_prep_k<<<dim3(40, 40, 4), dim3(32, 8), 0, stream>>>(w_q, w_k, w_v, w_o,
                                                         tk, tv, lkb, lvb, wtq);
  cvt_bf16_k<<<2048, 256, 0, stream>>>(hs, hsb, 2621440);

  const float qscale = 0.07905694150420949f;  // 1/sqrt(160)
  // fused QKV: WT rows 0..3839 = wtq|wtk|wtv, outputs qb|kb|vb contiguous
  gemm128_k<false, true><<<dim3(64, 30), 256, 0, stream>>>(hsb, wtq, qb, nullptr, qscale);
  vtrans_k<<<dim3(128, 40, 2), dim3(32, 8), 0, stream>>>(vb, vtb);
  attn_k<<<dim3(1024), 256, 0, stream>>>(qb, kb, vtb, aob, vb, ml);
  merge_k<<<dim3(5120), 256, 0, stream>>>(aob, vb, ml, merged);
  gemm128_k<true, false><<<dim3(64, 10), 256, 0, stream>>>(merged, wto, (void*)out, b_o, 1.0f);
}

// Round 11
// 358.239 us; speedup vs baseline: 1.4580x; 1.4580x over previous
//
#include <hip/hip_runtime.h>
#include <stdint.h>

typedef __attribute__((ext_vector_type(8))) __bf16 bf16x8;
typedef __attribute__((ext_vector_type(2))) __bf16 bf16x2;
typedef __attribute__((ext_vector_type(4))) float f32x4;
typedef __attribute__((ext_vector_type(16))) float f32x16;
typedef unsigned short u16;

#define LOG2E 1.44269504088896f

static_assert(sizeof(bf16x8) == 16, "bf16x8 must be 16B");

__device__ __forceinline__ u16 f2bf(float f) {
  unsigned u = __builtin_bit_cast(unsigned, f);
  u += 0x7fffu + ((u >> 16) & 1u);   // round-to-nearest-even
  return (u16)(u >> 16);
}

__device__ __forceinline__ void load_lds16(const void* g, void* l) {
  __builtin_amdgcn_global_load_lds((const __attribute__((address_space(1))) void*)g,
                                   (__attribute__((address_space(3))) void*)l, 16, 0, 0);
}

// ---------------- prep: tmp = W @ A  ([1280,1280]@[1280,4]) ----------------
__global__ __launch_bounds__(256) void lora_tmp_k(
    const float* __restrict__ wk, const float* __restrict__ wv,
    const float* __restrict__ ka, const float* __restrict__ va,
    float* __restrict__ tk, float* __restrict__ tv) {
  const int i = blockIdx.x;
  const float* W = blockIdx.y ? wv : wk;
  const float* A = blockIdx.y ? va : ka;
  float* T = blockIdx.y ? tv : tk;
  float s0 = 0.f, s1 = 0.f, s2 = 0.f, s3 = 0.f;
  for (int j = threadIdx.x; j < 1280; j += 256) {
    float w = W[(size_t)i * 1280 + j];
    float4 a4 = *(const float4*)(A + (size_t)j * 4);
    s0 += w * a4.x; s1 += w * a4.y; s2 += w * a4.z; s3 += w * a4.w;
  }
#pragma unroll
  for (int m = 1; m < 64; m <<= 1) {
    s0 += __shfl_xor(s0, m); s1 += __shfl_xor(s1, m);
    s2 += __shfl_xor(s2, m); s3 += __shfl_xor(s3, m);
  }
  __shared__ float red[4][4];
  const int wv_ = threadIdx.x >> 6;
  if ((threadIdx.x & 63) == 0) {
    red[wv_][0] = s0; red[wv_][1] = s1; red[wv_][2] = s2; red[wv_][3] = s3;
  }
  __syncthreads();
  if (threadIdx.x < 4) {
    float r = red[0][threadIdx.x] + red[1][threadIdx.x] + red[2][threadIdx.x] + red[3][threadIdx.x];
    T[(size_t)i * 4 + threadIdx.x] = r;
  }
}

// --- prep (fused x4): WT[z][o][i] = bf16( W_z[i][o] + lora_z ) , z=0..3 ----
__global__ void wt_prep_k(const float* __restrict__ wq, const float* __restrict__ wk,
                          const float* __restrict__ wv, const float* __restrict__ wo,
                          const float* __restrict__ tk, const float* __restrict__ tv,
                          const float* __restrict__ lkb, const float* __restrict__ lvb,
                          u16* __restrict__ WTbase) {
  const int z = blockIdx.z;
  const float* W = (z == 0) ? wq : (z == 1) ? wk : (z == 2) ? wv : wo;
  const float* tmp = (z == 1) ? tk : (z == 2) ? tv : nullptr;
  const float* LB = (z == 1) ? lkb : (z == 2) ? lvb : nullptr;
  u16* WT = WTbase + (size_t)z * 1638400;
  __shared__ float tile[32][33];
  const int o0 = blockIdx.x * 32, i0 = blockIdx.y * 32;
  const int tx = threadIdx.x, ty = threadIdx.y;
#pragma unroll
  for (int kk = 0; kk < 4; ++kk) {
    int i = i0 + ty + kk * 8, o = o0 + tx;
    float v = W[(size_t)i * 1280 + o];
    if (tmp) {
      float4 t = *(const float4*)(tmp + (size_t)i * 4);
      v += t.x * LB[o] + t.y * LB[1280 + o] + t.z * LB[2560 + o] + t.w * LB[3840 + o];
    }
    tile[ty + kk * 8][tx] = v;
  }
  __syncthreads();
#pragma unroll
  for (int kk = 0; kk < 4; ++kk) {
    int o = o0 + ty + kk * 8, i = i0 + tx;
    WT[(size_t)o * 1280 + i] = f2bf(tile[tx][ty + kk * 8]);
  }
}

// ---------------- fp32 -> bf16 convert (float4 vectorized) ----------------
__global__ __launch_bounds__(256) void cvt_bf16_k(const float* __restrict__ in,
                                                  u16* __restrict__ out, int n4) {
  for (int i = blockIdx.x * 256 + threadIdx.x; i < n4; i += gridDim.x * 256) {
    float4 v = ((const float4*)in)[i];
    ushort4 o;
    o.x = f2bf(v.x); o.y = f2bf(v.y); o.z = f2bf(v.z); o.w = f2bf(v.w);
    ((ushort4*)out)[i] = o;
  }
}

// --------- V [B*S,1280] -> VT [B*1280, 4096] (bf16 tiled transpose) --------
__global__ void vtrans_k(const u16* __restrict__ V, u16* __restrict__ VT) {
  __shared__ u16 tile[32][33];
  const int s0 = blockIdx.x * 32, c0 = blockIdx.y * 32, b = blockIdx.z;
  const int tx = threadIdx.x, ty = threadIdx.y;
#pragma unroll
  for (int kk = 0; kk < 4; ++kk)
    tile[ty + kk * 8][tx] = V[(size_t)(b * 4096 + s0 + ty + kk * 8) * 1280 + c0 + tx];
  __syncthreads();
#pragma unroll
  for (int kk = 0; kk < 4; ++kk)
    VT[(size_t)(b * 1280 + c0 + ty + kk * 8) * 4096 + s0 + tx] = tile[tx][ty + kk * 8];
}

// ------------------- 128x128-tile bf16 MFMA GEMM (BK=64) -------------------
// m97-shape: single-buffered A/B tiles, BK=64 -> 20 barrier-drain events
// (vs 40 at BK=32), 32 MFMA per drain. LDS rows = exactly 8 x 16B chunks,
// involution swizzle slot = c ^ (row&7) (attn-proven): staging is exactly
// 4 gload_lds/thread (no conditionals, pre-swizzled global source), and
// every fragment b128 read is bank-uniform (8 lanes/bank, optimal 8-cyc).
// FUSED3: B is three contiguous [1280,1280] weight blocks (rows 0..3839) and
// the output is three contiguous [8192,1280] buffers; oscale applies to sub 0.
template <bool F32OUT, bool FUSED3>
__global__ __launch_bounds__(256) void gemm128_k(
    const u16* __restrict__ A, const u16* __restrict__ WT,
    void* __restrict__ outp, const float* __restrict__ bias, float oscale) {
  __shared__ __align__(16) u16 lds[2 * 128 * 64];  // A[8192] + B[8192] u16 = 32KB
  u16* ldsA = lds;
  u16* ldsB = lds + 128 * 64;
  const int tid = threadIdx.x;
  const int lane = tid & 63, lrow = lane & 15, lhi = lane >> 4;
  const int w = tid >> 6, wm = w >> 1, wn = w & 1;
  const size_t M0 = (size_t)blockIdx.x * 128, N0 = (size_t)blockIdx.y * 128;
  const int wb = tid & 192;
  f32x4 acc[4][4] = {};

  for (int k0 = 0; k0 < 1280; k0 += 64) {
#pragma unroll
    for (int j = 0; j < 4; ++j) {
      int i = j * 256 + tid;
      int row = i >> 3, c = i & 7;
      int cg = c ^ (row & 7);
      load_lds16(A + (M0 + row) * 1280 + k0 + cg * 8, ldsA + (j * 256 + wb) * 8);
    }
#pragma unroll
    for (int j = 0; j < 4; ++j) {
      int i = j * 256 + tid;
      int row = i >> 3, c = i & 7;
      int cg = c ^ (row & 7);
      load_lds16(WT + (N0 + row) * 1280 + k0 + cg * 8, ldsB + (j * 256 + wb) * 8);
    }
    __syncthreads();
    bf16x8 af[2][4], bfr[2][4];
#pragma unroll
    for (int kk = 0; kk < 2; ++kk) {
      const int slot = ((kk * 4 + lhi) ^ (lrow & 7)) * 8;
#pragma unroll
      for (int m = 0; m < 4; ++m)
        af[kk][m] = *(const bf16x8*)(ldsA + (wm * 64 + m * 16 + lrow) * 64 + slot);
#pragma unroll
      for (int n = 0; n < 4; ++n)
        bfr[kk][n] = *(const bf16x8*)(ldsB + (wn * 64 + n * 16 + lrow) * 64 + slot);
    }
#pragma unroll
    for (int kk = 0; kk < 2; ++kk)
#pragma unroll
      for (int m = 0; m < 4; ++m)
#pragma unroll
        for (int n = 0; n < 4; ++n)
          acc[m][n] = __builtin_amdgcn_mfma_f32_16x16x32_bf16(af[kk][m], bfr[kk][n], acc[m][n], 0, 0, 0);
    __syncthreads();
  }

  const float sc = FUSED3 ? (N0 < 1280 ? oscale : 1.0f) : oscale;
  const size_t obase = FUSED3 ? (size_t)(N0 / 1280) * 10485760 : 0;
  const size_t ncol0 = FUSED3 ? (N0 % 1280) : N0;
#pragma unroll
  for (int m = 0; m < 4; ++m)
#pragma unroll
    for (int n = 0; n < 4; ++n)
#pragma unroll
      for (int r = 0; r < 4; ++r) {
        size_t row = M0 + wm * 64 + m * 16 + lhi * 4 + r;
        size_t col = ncol0 + wn * 64 + n * 16 + lrow;
        float v = acc[m][n][r];
        if (F32OUT)
          ((float*)outp)[row * 1280 + col] = v + bias[col];
        else
          ((u16*)outp)[obase + row * 1280 + col] = f2bf(v * sc);
      }
}

// --------------------------- flash attention (R8 proven) -------------------
// grid 512 (flat, XCD-swizzled), 256 thr = 4 waves x 32 q-cols. QBLK=128,
// KVBLK=64. nid=(x&7)*64+(x>>3): XCD k hosts heads {2k,2k+1}. Swapped QK^T
// (S^T = mfma(K,Q), 32x32x16); in-register softmax; P assembled in-register.
// QK(t)+PV(t-1) MFMA pairing; counted vmcnt (5/10); 2 barriers/tile; K dbuf +
// V dbuf = 80 KB. Occupancy is register-bound at 2 waves/SIMD (~208 combined
// VGPR+AGPR) — R10's seq-split proved LDS was never the limiter.

#define QK_CLUSTER(KCUR)                                                        \
  {                                                                             \
    f32x16 zz = {};                                                             \
    sacc0 = zz; sacc1 = zz;                                                     \
    __builtin_amdgcn_s_setprio(1);                                              \
    _Pragma("unroll")                                                           \
    for (int kf = 0; kf < 10; ++kf) {                                           \
      const int c_ = 2 * kf + lhi5;                                             \
      {                                                                         \
        const int row_ = l31;                                                   \
        const int slot_ = (kf < 8) ? ((c_ & 24) | ((c_ ^ row_) & 7))            \
                                   : (16 + ((c_ ^ (row_ >> 1)) & 3));           \
        bf16x8 ka_ = *(const bf16x8*)((KCUR) + row_ * 160 + slot_ * 8);         \
        sacc0 = __builtin_amdgcn_mfma_f32_32x32x16_bf16(ka_, qf[kf], sacc0, 0, 0, 0); \
      }                                                                         \
      {                                                                         \
        const int row_ = 32 + l31;                                              \
        const int slot_ = (kf < 8) ? ((c_ & 24) | ((c_ ^ row_) & 7))            \
                                   : (16 + ((c_ ^ (row_ >> 1)) & 3));           \
        bf16x8 ka_ = *(const bf16x8*)((KCUR) + row_ * 160 + slot_ * 8);         \
        sacc1 = __builtin_amdgcn_mfma_f32_32x32x16_bf16(ka_, qf[kf], sacc1, 0, 0, 0); \
      }                                                                         \
    }                                                                           \
    __builtin_amdgcn_s_setprio(0);                                              \
  }

#define PV_CLUSTER(VSRC)                                                        \
  {                                                                             \
    __builtin_amdgcn_s_setprio(1);                                              \
    _Pragma("unroll")                                                           \
    for (int kf = 0; kf < 4; ++kf) {                                            \
      const int base_ = (kf >> 1) * 8 + (kf & 1) * 4;                           \
      unsigned xa_ = xp[base_ + 0], xb_ = xp[base_ + 1];                        \
      unsigned xc_ = xp[base_ + 2], xd_ = xp[base_ + 3];                        \
      unsigned sa_ = __shfl_xor((int)xa_, 32), sb_ = __shfl_xor((int)xb_, 32);  \
      unsigned sc_ = __shfl_xor((int)xc_, 32), sd_ = __shfl_xor((int)xd_, 32);  \
      uint4 pw_;                                                                \
      pw_.x = lo32 ? xa_ : sc_;                                                 \
      pw_.y = lo32 ? xb_ : sd_;                                                 \
      pw_.z = lo32 ? sa_ : xc_;                                                 \
      pw_.w = lo32 ? sb_ : xd_;                                                 \
      bf16x8 pB_ = __builtin_bit_cast(bf16x8, pw_);                             \
      const int c_ = 2 * kf + lhi5;                                             \
      _Pragma("unroll")                                                         \
      for (int dm = 0; dm < 5; ++dm) {                                          \
        const int row_ = dm * 32 + l31;                                         \
        bf16x8 va_ = *(const bf16x8*)((VSRC) + row_ * 64 + ((c_ ^ (row_ & 7)) * 8)); \
        o[dm] = __builtin_amdgcn_mfma_f32_32x32x16_bf16(va_, pB_, o[dm], 0, 0, 0); \
      }                                                                         \
    }                                                                           \
    __builtin_amdgcn_s_setprio(0);                                              \
  }

#define SOFTMAX_STEP()                                                          \
  {                                                                             \
    float tmx_[8];                                                              \
    _Pragma("unroll")                                                           \
    for (int i = 0; i < 8; ++i)                                                 \
      tmx_[i] = fmaxf(fmaxf(sacc0[i], sacc0[i + 8]),                            \
                      fmaxf(sacc1[i], sacc1[i + 8]));                           \
    float mx_ = fmaxf(fmaxf(fmaxf(tmx_[0], tmx_[1]), fmaxf(tmx_[2], tmx_[3])),  \
                      fmaxf(fmaxf(tmx_[4], tmx_[5]), fmaxf(tmx_[6], tmx_[7]))); \
    mx_ = fmaxf(mx_, __shfl_xor(mx_, 32));                                      \
    if (__any(mx_ - m_run > 8.0f)) {                                            \
      float mnew_ = fmaxf(m_run, mx_);                                          \
      float al_ = __builtin_amdgcn_exp2f((m_run - mnew_) * LOG2E);              \
      l_run *= al_; m_run = mnew_; mLog = m_run * LOG2E;                        \
      _Pragma("unroll")                                                         \
      for (int dm = 0; dm < 5; ++dm)                                            \
        _Pragma("unroll")                                                       \
        for (int i = 0; i < 16; ++i) o[dm][i] *= al_;                           \
    }                                                                           \
    float rs0_ = 0.f, rs1_ = 0.f, rs2_ = 0.f, rs3_ = 0.f;                       \
    _Pragma("unroll")                                                           \
    for (int r = 0; r < 8; ++r) {                                               \
      float p0_ = __builtin_amdgcn_exp2f(fmaf(sacc0[2 * r], LOG2E, -mLog));     \
      float p1_ = __builtin_amdgcn_exp2f(fmaf(sacc0[2 * r + 1], LOG2E, -mLog)); \
      if ((r & 3) == 0) rs0_ += p0_ + p1_;                                      \
      else if ((r & 3) == 1) rs1_ += p0_ + p1_;                                 \
      else if ((r & 3) == 2) rs2_ += p0_ + p1_;                                 \
      else rs3_ += p0_ + p1_;                                                   \
      bf16x2 pk_; pk_[0] = (__bf16)p0_; pk_[1] = (__bf16)p1_;                   \
      xp[r] = __builtin_bit_cast(unsigned, pk_);                                \
    }                                                                           \
    _Pragma("unroll")                                                           \
    for (int r = 0; r < 8; ++r) {                                               \
      float p0_ = __builtin_amdgcn_exp2f(fmaf(sacc1[2 * r], LOG2E, -mLog));     \
      float p1_ = __builtin_amdgcn_exp2f(fmaf(sacc1[2 * r + 1], LOG2E, -mLog)); \
      if ((r & 3) == 0) rs0_ += p0_ + p1_;                                      \
      else if ((r & 3) == 1) rs1_ += p0_ + p1_;                                 \
      else if ((r & 3) == 2) rs2_ += p0_ + p1_;                                 \
      else rs3_ += p0_ + p1_;                                                   \
      bf16x2 pk_; pk_[0] = (__bf16)p0_; pk_[1] = (__bf16)p1_;                   \
      xp[8 + r] = __builtin_bit_cast(unsigned, pk_);                            \
    }                                                                           \
    float rs_ = (rs0_ + rs1_) + (rs2_ + rs3_);                                  \
    rs_ += __shfl_xor(rs_, 32);                                                 \
    l_run += rs_;                                                               \
  }

#define STAGE_K(KV0, DST)                                                       \
  {                                                                             \
    _Pragma("unroll")                                                           \
    for (int j = 0; j < 5; ++j) {                                               \
      int i_ = j * 256 + tid;                                                   \
      int row_ = i_ / 20, cl_ = i_ % 20;                                        \
      int cg_ = (cl_ < 16) ? ((cl_ & 24) | ((cl_ ^ row_) & 7))                  \
                           : (16 + ((cl_ ^ (row_ >> 1)) & 3));                  \
      load_lds16(Kg + (size_t)((KV0) + row_) * 1280 + cg_ * 8,                  \
                 (DST) + (j * 256 + wb) * 8);                                   \
    }                                                                           \
  }

#define STAGE_V(KV0, DST)                                                       \
  {                                                                             \
    _Pragma("unroll")                                                           \
    for (int j = 0; j < 5; ++j) {                                               \
      int i_ = j * 256 + tid;                                                   \
      int row_ = i_ >> 3, cl_ = i_ & 7;                                         \
      int cg_ = cl_ ^ (row_ & 7);                                               \
      load_lds16(VTg + (size_t)row_ * 4096 + (KV0) + cg_ * 8,                   \
                 (DST) + (j * 256 + wb) * 8);                                   \
    }                                                                           \
  }

#define WAITB(N)                                                                \
  asm volatile("s_waitcnt vmcnt(" #N ")" ::: "memory");                         \
  __builtin_amdgcn_s_barrier();                                                 \
  __builtin_amdgcn_sched_barrier(0);

__global__ __launch_bounds__(256, 2) void attn_k(
    const u16* __restrict__ Q, const u16* __restrict__ K,
    const u16* __restrict__ VT, u16* __restrict__ AO) {
  __shared__ __align__(16) u16 lds_all[40960];  // kb0 kb1 vt0 vt1, 10240 u16 each
  u16* const kb0 = lds_all;
  u16* const kb1 = lds_all + 10240;
  u16* const vt0 = lds_all + 20480;
  u16* const vt1 = lds_all + 30720;
  const int tid = threadIdx.x;
  const int lane = tid & 63;
  const int l31 = lane & 31, lhi5 = lane >> 5;
  const int lo32 = (lane < 32);
  const int w = tid >> 6;
  const int nid = ((blockIdx.x & 7) << 6) | (blockIdx.x >> 3);
  const int bh = nid >> 5, qt = nid & 31;
  const int b = bh >> 3, h = bh & 7;
  const int wb = tid & 192;

  const u16* Kg = K + (size_t)b * 4096 * 1280 + h * 160;
  const u16* VTg = VT + ((size_t)b * 1280 + h * 160) * 4096;

  bf16x8 qf[10];
  const u16* Qg = Q + (size_t)(b * 4096 + qt * 128 + w * 32 + l31) * 1280 + h * 160 + lhi5 * 8;
#pragma unroll
  for (int kf = 0; kf < 10; ++kf) qf[kf] = *(const bf16x8*)(Qg + kf * 16);
#pragma unroll
  for (int kf = 0; kf < 10; ++kf) asm volatile("" : "+v"(qf[kf]));  // drain Q before staging

  f32x16 o[5] = {};
  f32x16 sacc0, sacc1;
  unsigned xp[16];
  float m_run = -1e30f, l_run = 0.f;
  float mLog = m_run * LOG2E;

  // ---- t = 0 (peeled: no PV) ----
  STAGE_K(0, kb0);
  WAITB(0);
  STAGE_K(64, kb1);
  STAGE_V(0, vt0);
  QK_CLUSTER(kb0);
  SOFTMAX_STEP();

  // ---- main loop t = 1..62 (two parities unrolled) ----
  for (int tp = 0; tp < 31; ++tp) {
    const int t1 = 2 * tp + 1;
    WAITB(5);                       // K(t) landed; V(t-1) still in flight
    STAGE_K((t1 + 1) * 64, kb0);
    STAGE_V(t1 * 64, vt1);
    QK_CLUSTER(kb1);
    WAITB(10);                      // V(t-1) landed; K(t+1),V(t) in flight
    PV_CLUSTER(vt0);
    SOFTMAX_STEP();
    WAITB(5);
    STAGE_K((t1 + 2) * 64, kb1);
    STAGE_V((t1 + 1) * 64, vt0);
    QK_CLUSTER(kb0);
    WAITB(10);
    PV_CLUSTER(vt1);
    SOFTMAX_STEP();
  }

  // ---- t = 63 (peeled: no K prefetch) ----
  WAITB(5);                         // K(63) landed
  STAGE_V(63 * 64, vt1);
  QK_CLUSTER(kb1);
  WAITB(5);                         // V(62) landed; V(63) in flight
  PV_CLUSTER(vt0);
  SOFTMAX_STEP();

  // ---- t = 64 (epilogue: final PV) ----
  WAITB(0);                         // V(63) landed
  PV_CLUSTER(vt1);

  // epilogue: per-wave LDS transpose + coalesced 16B stores
  float invl = 1.f / l_run;
  u16* tr = lds_all + w * 5376;  // 32 rows x 168 u16
#pragma unroll
  for (int dm = 0; dm < 5; ++dm)
#pragma unroll
    for (int k = 0; k < 4; ++k) {
      int d = dm * 32 + k * 8 + lhi5 * 4;
      unsigned lo_ = (unsigned)f2bf(o[dm][4 * k + 0] * invl) |
                     ((unsigned)f2bf(o[dm][4 * k + 1] * invl) << 16);
      unsigned hi_ = (unsigned)f2bf(o[dm][4 * k + 2] * invl) |
                     ((unsigned)f2bf(o[dm][4 * k + 3] * invl) << 16);
      uint2 u; u.x = lo_; u.y = hi_;
      *(uint2*)(tr + l31 * 168 + d) = u;
    }
  asm volatile("s_waitcnt lgkmcnt(0)" ::: "memory");
  __builtin_amdgcn_sched_barrier(0);
  const size_t qg0 = (size_t)(b * 4096 + qt * 128 + w * 32);
#pragma unroll
  for (int it = 0; it < 10; ++it) {
    int idx = it * 64 + lane;
    int row = idx / 20, cc = idx % 20;
    bf16x8 vch = *(const bf16x8*)(tr + row * 168 + cc * 8);
    *(bf16x8*)(AO + (qg0 + row) * 1280 + h * 160 + cc * 8) = vch;
  }
}

// ---------------------------------------------------------------------------
extern "C" void kernel_launch(void* const* d_in, const int* in_sizes, int n_in,
                              void* d_out, int out_size, void* d_ws, size_t ws_size,
                              hipStream_t stream) {
  const float* hs  = (const float*)d_in[0];
  const float* w_q = (const float*)d_in[1];
  const float* w_k = (const float*)d_in[2];
  const float* w_v = (const float*)d_in[3];
  const float* lka = (const float*)d_in[4];
  const float* lkb = (const float*)d_in[5];
  const float* lva = (const float*)d_in[6];
  const float* lvb = (const float*)d_in[7];
  const float* w_o = (const float*)d_in[8];
  const float* b_o = (const float*)d_in[9];
  float* out = (float*)d_out;
  char* ws = (char*)d_ws;

  const size_t KA  = 0;                      // 1280*4 f32
  const size_t VA  = 20480;
  const size_t WTQ = 40960;                  // 1280*1280 bf16 each; Q,K,V,O contiguous
  const size_t WTO = WTQ + 3 * 3276800;
  const size_t HSB = WTO + 3276800;          // 8192*1280 bf16 each below; q,k,v contiguous
  const size_t QB  = HSB + 20971520;
  const size_t KB  = QB + 20971520;
  const size_t VB  = KB + 20971520;
  const size_t VTB = VB + 20971520;
  const size_t AOB = VTB + 20971520;
  const size_t END = AOB + 20971520;
  if (ws_size < END) return;  // leaves poison -> clear validation failure

  float* tk = (float*)(ws + KA);
  float* tv = (float*)(ws + VA);
  u16* wtq = (u16*)(ws + WTQ);
  u16* wto = (u16*)(ws + WTO);
  u16* hsb = (u16*)(ws + HSB);
  u16* qb  = (u16*)(ws + QB);
  u16* kb  = (u16*)(ws + KB);
  u16* vb  = (u16*)(ws + VB);
  u16* vtb = (u16*)(ws + VTB);
  u16* aob = (u16*)(ws + AOB);

  lora_tmp_k<<<dim3(1280, 2), 256, 0, stream>>>(w_k, w_v, lka, lva, tk, tv);
  wt_prep_k<<<dim3(40, 40, 4), dim3(32, 8), 0, stream>>>(w_q, w_k, w_v, w_o,
                                                         tk, tv, lkb, lvb, wtq);
  cvt_bf16_k<<<2048, 256, 0, stream>>>(hs, hsb, 2621440);

  const float qscale = 0.07905694150420949f;  // 1/sqrt(160)
  // fused QKV: WT rows 0..3839 = wtq|wtk|wtv, outputs qb|kb|vb contiguous
  gemm128_k<false, true><<<dim3(64, 30), 256, 0, stream>>>(hsb, wtq, qb, nullptr, qscale);
  vtrans_k<<<dim3(128, 40, 2), dim3(32, 8), 0, stream>>>(vb, vtb);
  attn_k<<<dim3(512), 256, 0, stream>>>(qb, kb, vtb, aob);
  gemm128_k<true, false><<<dim3(64, 10), 256, 0, stream>>>(aob, wto, (void*)out, b_o, 1.0f);
}